// Round 10
// baseline (89.785 us; speedup 1.0000x reference)
//
#include <hip/hip_runtime.h>

// ColPali2Loss: sv in-batch softmax CE + mv MaxSim margin loss.
// B=64, Nq=32, Ns=1024, D=128. Outputs: [sv_loss, mv_loss, total] f32.
// Fused mv: g2l16 f32 tile (prefetch t+1 before compute t), LDS cvt to
// swizzled bf16 dbuf, rt=4 x 8 waves (512 rows/block), 4 passes over dm.

typedef __attribute__((ext_vector_type(8))) short short8;
typedef __attribute__((ext_vector_type(4))) float f32x4;

static __device__ __forceinline__ unsigned short f2bf(float f) {
  unsigned int u = __float_as_uint(f);
  u += 0x7fffu + ((u >> 16) & 1u);  // RNE to bf16
  return (unsigned short)(u >> 16);
}

static __device__ __forceinline__ void g2l16(const void* g, void* l) {
  __builtin_amdgcn_global_load_lds(
      (const __attribute__((address_space(1))) unsigned int*)g,
      (__attribute__((address_space(3))) unsigned int*)l, 16, 0, 0);
}

// ---------------- fused mv GEMM partials (+ sv in last 8 blocks) ----------
// 512 mv blocks, 512 threads (8 waves): 512 q-rows x 1 doc x 512 s.
// wgid = rb + 4*c + 256*sc ; sv blocks are wgid 512..519.
// LDS: [0,32K) f32 tile | [32K,64K) bf16 dbuf | [64K,66K) rowmax
__global__ __launch_bounds__(512, 4) void mv_kernel(
    const float* __restrict__ qm, const float* __restrict__ dm,
    const float* __restrict__ qs, const float* __restrict__ ds,
    float* __restrict__ part, float* __restrict__ svp) {
  __shared__ __align__(16) unsigned char smem[67584];

  const int tid = threadIdx.x;
  const int ln = tid & 63;
  const int wv = tid >> 6;  // 0..7
  const int wgid = blockIdx.x;

  if (wgid >= 512) {
    // ---- sv block: rows 8*rb .. 8*rb+7 of the 64x64 score matrix ----
    const int rb = wgid - 512;  // 0..7
    float* dl = (float*)smem;   // [64][129] padded f32 (33024 B)
    for (int i = tid; i < 8192; i += 512)
      dl[(i >> 7) * 129 + (i & 127)] = ds[i];
    __syncthreads();
    const int cc = ln;            // candidate doc = lane
    const int row = rb * 8 + wv;  // one row per wave
    const float* q = qs + (size_t)row * 128;
    float acc = 0.f;
#pragma unroll
    for (int k = 0; k < 128; ++k) acc += q[k] * dl[cc * 129 + k];
    float m = acc;
    for (int d = 1; d < 64; d <<= 1) m = fmaxf(m, __shfl_xor(m, d));
    float e = expf(acc - m);
    float ssum = e;
    for (int d = 1; d < 64; d <<= 1) ssum += __shfl_xor(ssum, d);
    const float lp = acc - m - logf(ssum);
    const float diag = __shfl(lp, row);
    if (ln == 0) svp[row] = -diag;
    return;
  }

  const int rb = wgid & 3;         // 0..3 : 512-row chunk
  const int c = (wgid >> 2) & 63;  // doc
  const int sc = wgid >> 8;        // 0..1 : 512-s half

  const int lrow = ln & 15;
  const int lkg = ln >> 4;

  float* fbuf = (float*)smem;              // 8192 f32 (64 s x 128)
  float* rowmax = (float*)(smem + 65536);  // 512 f32

  const float* dmF = dm + (size_t)c * 131072 + (size_t)sc * 65536;

  // prologue: issue f32 stage of tile 0 (wave-uniform LDS dest, r7 pattern)
#pragma unroll
  for (int i = 0; i < 4; ++i) {
    const int ch = wv * 4 + i;  // 32 chunks x 1 KB
    g2l16(dmF + ch * 256 + ln * 4, smem + ch * 1024);
  }

  // A fragments: 4 row-tiles x 4 k-chunks from qm f32 (r1-verified cvt),
  // loaded while the stage is in flight.
  short8 qf[4][4];
#pragma unroll
  for (int rt = 0; rt < 4; ++rt) {
    const int row = rb * 512 + wv * 64 + rt * 16 + lrow;
    const float* qp = qm + (size_t)row * 128 + lkg * 8;
#pragma unroll
    for (int kk = 0; kk < 4; ++kk) {
      const float4 a = *(const float4*)(qp + kk * 32);
      const float4 b = *(const float4*)(qp + kk * 32 + 4);
      short8 f;
      f[0] = (short)f2bf(a.x); f[1] = (short)f2bf(a.y);
      f[2] = (short)f2bf(a.z); f[3] = (short)f2bf(a.w);
      f[4] = (short)f2bf(b.x); f[5] = (short)f2bf(b.y);
      f[6] = (short)f2bf(b.z); f[7] = (short)f2bf(b.w);
      qf[rt][kk] = f;
    }
  }

  f32x4 maxv[4];
#pragma unroll
  for (int rt = 0; rt < 4; ++rt)
#pragma unroll
    for (int r = 0; r < 4; ++r) maxv[rt][r] = -3.0e38f;

  __syncthreads();  // drains vmcnt: f32 tile 0 in fbuf

  // prologue cvt: fbuf -> bbuf[0] (r1-verified swizzled staging writes)
  {
    unsigned char* bb = smem + 32768;
#pragma unroll
    for (int i = 0; i < 2; ++i) {
      const int ch = tid + i * 512;  // 1024 16B out-chunks
      const int s = ch >> 4;
      const int kc = ch & 15;
      const float* p = fbuf + s * 128 + kc * 8;
      const float4 a = *(const float4*)p;
      const float4 b = *(const float4*)(p + 4);
      short8 w;
      w[0] = (short)f2bf(a.x); w[1] = (short)f2bf(a.y);
      w[2] = (short)f2bf(a.z); w[3] = (short)f2bf(a.w);
      w[4] = (short)f2bf(b.x); w[5] = (short)f2bf(b.y);
      w[6] = (short)f2bf(b.z); w[7] = (short)f2bf(b.w);
      *(short8*)(bb + s * 256 + ((kc * 16) ^ ((s & 7) << 4))) = w;
    }
  }

  for (int t = 0; t < 8; ++t) {
    __syncthreads();  // bbuf[t&1] writes visible; fbuf free (cvt consumed it)
    if (t < 7) {
      const float* gt = dmF + (t + 1) * 8192;
#pragma unroll
      for (int i = 0; i < 4; ++i) {
        const int ch = wv * 4 + i;
        g2l16(gt + ch * 256 + ln * 4, smem + ch * 1024);
      }
    }
    // compute on bbuf[t&1] while the stage flies
    const unsigned char* cur = smem + 32768 + (t & 1) * 16384;
#pragma unroll
    for (int cc = 0; cc < 4; ++cc) {
      const int s = cc * 16 + lrow;
      const unsigned char* bp = cur + s * 256;
      const int swz = (s & 7) << 4;
      short8 df[4];
#pragma unroll
      for (int kk = 0; kk < 4; ++kk)
        df[kk] = *(const short8*)(bp + ((kk * 64 + lkg * 16) ^ swz));
#pragma unroll
      for (int rt = 0; rt < 4; ++rt) {
        f32x4 a = {0.f, 0.f, 0.f, 0.f};
#pragma unroll
        for (int kk = 0; kk < 4; ++kk)
          a = __builtin_amdgcn_mfma_f32_16x16x32_bf16(qf[rt][kk], df[kk], a,
                                                      0, 0, 0);
#pragma unroll
        for (int r = 0; r < 4; ++r) maxv[rt][r] = fmaxf(maxv[rt][r], a[r]);
      }
    }
    __syncthreads();  // drains vmcnt: f32(t+1) landed; bbuf reads done
    if (t < 7) {
      unsigned char* bb = smem + 32768 + ((t + 1) & 1) * 16384;
#pragma unroll
      for (int i = 0; i < 2; ++i) {
        const int ch = tid + i * 512;
        const int s = ch >> 4;
        const int kc = ch & 15;
        const float* p = fbuf + s * 128 + kc * 8;
        const float4 a = *(const float4*)p;
        const float4 b = *(const float4*)(p + 4);
        short8 w;
        w[0] = (short)f2bf(a.x); w[1] = (short)f2bf(a.y);
        w[2] = (short)f2bf(a.z); w[3] = (short)f2bf(a.w);
        w[4] = (short)f2bf(b.x); w[5] = (short)f2bf(b.y);
        w[6] = (short)f2bf(b.z); w[7] = (short)f2bf(b.w);
        *(short8*)(bb + s * 256 + ((kc * 16) ^ ((s & 7) << 4))) = w;
      }
    }
  }

  // max over 16 s-column lanes (C/D: col=lrow, row=lkg*4+r)
#pragma unroll
  for (int rt = 0; rt < 4; ++rt)
#pragma unroll
    for (int r = 0; r < 4; ++r) {
      float v = maxv[rt][r];
      v = fmaxf(v, __shfl_xor(v, 1));
      v = fmaxf(v, __shfl_xor(v, 2));
      v = fmaxf(v, __shfl_xor(v, 4));
      v = fmaxf(v, __shfl_xor(v, 8));
      if (lrow == 0) rowmax[wv * 64 + rt * 16 + lkg * 4 + r] = v;
    }
  __syncthreads();

  // coalesced partial-max store: one row per thread
  const size_t pb = (size_t)(c * 2 + sc) * 2048 + rb * 512;
  part[pb + tid] = rowmax[tid];
}

// ---------------- combine partials: scores[b][c] ----------------
__global__ void reduce_kernel(const float* __restrict__ part,
                              float* __restrict__ scores) {
  const int c = blockIdx.x;   // 64
  const int t = threadIdx.x;  // 256
  const float* p0 = part + (size_t)(c * 2 + 0) * 2048;
  const float* p1 = part + (size_t)(c * 2 + 1) * 2048;
  float s = 0.f;
#pragma unroll
  for (int i = 0; i < 8; ++i) {
    const int r = t * 8 + i;
    s += fmaxf(p0[r], p1[r]);
  }
  s += __shfl_xor(s, 1);
  s += __shfl_xor(s, 2);
  if ((t & 3) == 0) scores[(t >> 2) * 64 + c] = s;
}

// ---------------- final: sv mean + margin loss + combine ----------------
__global__ void final_kernel(const float* __restrict__ scores,
                             const float* __restrict__ svp,
                             float* __restrict__ out) {
  const int b = threadIdx.x;  // 64
  float sv = svp[b];
  for (int d = 1; d < 64; d <<= 1) sv += __shfl_xor(sv, d);
  sv *= (1.0f / 64.0f);

  const float pos = scores[b * 64 + b];
  float neg = -3.0e38f;
  for (int c = 0; c < 64; ++c) {
    float v = scores[b * 64 + c] - (c == b ? 1.0e6f : 0.0f);
    neg = fmaxf(neg, v);
  }
  const float t = neg - pos;
  float sp = fmaxf(t, 0.f) + log1pf(expf(-fabsf(t)));
  for (int d = 1; d < 64; d <<= 1) sp += __shfl_xor(sp, d);
  if (b == 0) {
    const float mvl = sp / 64.0f;
    out[0] = sv;
    out[1] = mvl;
    out[2] = 0.5f * sv + 0.5f * mvl;
  }
}

// ======================= fallback (round-1, passing) =======================
__global__ void sv_kernel_fb(const float* __restrict__ qs,
                             const float* __restrict__ ds,
                             float* __restrict__ out_sv) {
  __shared__ float sc[64][64];
  const int tid = threadIdx.x;
  for (int p = tid; p < 4096; p += 256) {
    const int b = p >> 6, c = p & 63;
    const float4* qa = (const float4*)(qs + b * 128);
    const float4* da = (const float4*)(ds + c * 128);
    float acc = 0.f;
#pragma unroll
    for (int i = 0; i < 32; ++i) {
      const float4 x = qa[i], y = da[i];
      acc += x.x * y.x + x.y * y.y + x.z * y.z + x.w * y.w;
    }
    sc[b][c] = acc;
  }
  __syncthreads();
  if (tid < 64) {
    float m = -3.0e38f;
    for (int c = 0; c < 64; ++c) m = fmaxf(m, sc[tid][c]);
    float s = 0.f;
    for (int c = 0; c < 64; ++c) s += expf(sc[tid][c] - m);
    float lp = sc[tid][tid] - (m + logf(s));
    for (int d = 1; d < 64; d <<= 1) lp += __shfl_xor(lp, d);
    if (tid == 0) *out_sv = -lp / 64.0f;
  }
}

__global__ __launch_bounds__(256, 4) void mv_gemm_fb(
    const float* __restrict__ qm, const float* __restrict__ dm,
    float* __restrict__ scores) {
  __shared__ unsigned char dtb[64 * 256];
  __shared__ float rowmax[128];
  const int c = blockIdx.y;
  const int rb = blockIdx.x;
  const int tid = threadIdx.x;
  const int ln = tid & 63;
  const int wv = tid >> 6;
  const int lrow = ln & 15;
  const int lkg = ln >> 4;
  short8 qf[2][4];
#pragma unroll
  for (int rt = 0; rt < 2; ++rt) {
    const int row = rb * 128 + wv * 32 + rt * 16 + lrow;
    const float* qp = qm + (size_t)row * 128 + lkg * 8;
#pragma unroll
    for (int kk = 0; kk < 4; ++kk) {
      const float4 a = *(const float4*)(qp + kk * 32);
      const float4 b = *(const float4*)(qp + kk * 32 + 4);
      short8 f;
      f[0] = (short)f2bf(a.x); f[1] = (short)f2bf(a.y);
      f[2] = (short)f2bf(a.z); f[3] = (short)f2bf(a.w);
      f[4] = (short)f2bf(b.x); f[5] = (short)f2bf(b.y);
      f[6] = (short)f2bf(b.z); f[7] = (short)f2bf(b.w);
      qf[rt][kk] = f;
    }
  }
  f32x4 maxv[2];
#pragma unroll
  for (int rt = 0; rt < 2; ++rt)
#pragma unroll
    for (int r = 0; r < 4; ++r) maxv[rt][r] = -3.0e38f;
  const float* dbase = dm + (size_t)c * 1024 * 128;
  for (int t = 0; t < 16; ++t) {
    __syncthreads();
#pragma unroll
    for (int i = 0; i < 4; ++i) {
      const int ch = tid + i * 256;
      const int s = ch >> 4;
      const int kc = ch & 15;
      const float* p = dbase + (size_t)(t * 64 + s) * 128 + kc * 8;
      const float4 a = *(const float4*)p;
      const float4 b = *(const float4*)(p + 4);
      short8 w;
      w[0] = (short)f2bf(a.x); w[1] = (short)f2bf(a.y);
      w[2] = (short)f2bf(a.z); w[3] = (short)f2bf(a.w);
      w[4] = (short)f2bf(b.x); w[5] = (short)f2bf(b.y);
      w[6] = (short)f2bf(b.z); w[7] = (short)f2bf(b.w);
      *(short8*)(dtb + s * 256 + ((kc * 16) ^ ((s & 7) << 4))) = w;
    }
    __syncthreads();
#pragma unroll
    for (int cc = 0; cc < 4; ++cc) {
      const int s = cc * 16 + lrow;
      short8 df[4];
#pragma unroll
      for (int kk = 0; kk < 4; ++kk)
        df[kk] = *(const short8*)(dtb + s * 256 +
                                  ((kk * 64 + lkg * 16) ^ ((s & 7) << 4)));
#pragma unroll
      for (int rt = 0; rt < 2; ++rt) {
        f32x4 acc = {0.f, 0.f, 0.f, 0.f};
#pragma unroll
        for (int kk = 0; kk < 4; ++kk)
          acc = __builtin_amdgcn_mfma_f32_16x16x32_bf16(qf[rt][kk], df[kk],
                                                        acc, 0, 0, 0);
#pragma unroll
        for (int r = 0; r < 4; ++r) maxv[rt][r] = fmaxf(maxv[rt][r], acc[r]);
      }
    }
  }
#pragma unroll
  for (int rt = 0; rt < 2; ++rt)
#pragma unroll
    for (int r = 0; r < 4; ++r) {
      float v = maxv[rt][r];
      v = fmaxf(v, __shfl_xor(v, 1));
      v = fmaxf(v, __shfl_xor(v, 2));
      v = fmaxf(v, __shfl_xor(v, 4));
      v = fmaxf(v, __shfl_xor(v, 8));
      maxv[rt][r] = v;
    }
  if (lrow == 0) {
#pragma unroll
    for (int rt = 0; rt < 2; ++rt)
#pragma unroll
      for (int r = 0; r < 4; ++r)
        rowmax[wv * 32 + rt * 16 + lkg * 4 + r] = maxv[rt][r];
  }
  __syncthreads();
  if (tid < 128) {
    float v = rowmax[tid];
    v += __shfl_xor(v, 1);
    v += __shfl_xor(v, 2);
    v += __shfl_xor(v, 4);
    v += __shfl_xor(v, 8);
    v += __shfl_xor(v, 16);
    if ((tid & 31) == 0) scores[(rb * 4 + (tid >> 5)) * 64 + c] = v;
  }
}

__global__ void final_fb(const float* __restrict__ scores,
                         const float* __restrict__ sv_ptr,
                         float* __restrict__ out) {
  const int b = threadIdx.x;
  const float pos = scores[b * 64 + b];
  float neg = -3.0e38f;
  for (int c = 0; c < 64; ++c) {
    float v = scores[b * 64 + c] - (c == b ? 1.0e6f : 0.0f);
    neg = fmaxf(neg, v);
  }
  const float t = neg - pos;
  float sp = fmaxf(t, 0.f) + log1pf(expf(-fabsf(t)));
  for (int d = 1; d < 64; d <<= 1) sp += __shfl_xor(sp, d);
  if (b == 0) {
    const float mvl = sp / 64.0f;
    const float sv = *sv_ptr;
    out[0] = sv;
    out[1] = mvl;
    out[2] = 0.5f * sv + 0.5f * mvl;
  }
}

extern "C" void kernel_launch(void* const* d_in, const int* in_sizes, int n_in,
                              void* d_out, int out_size, void* d_ws,
                              size_t ws_size, hipStream_t stream) {
  const float* qs = (const float*)d_in[0];  // (64,128)
  const float* ds = (const float*)d_in[1];  // (64,128)
  const float* qm = (const float*)d_in[2];  // (64,32,128)
  const float* dm = (const float*)d_in[3];  // (64,1024,128)
  float* out = (float*)d_out;

  // ws: part 1 MiB | scores 16 KiB | svp 256 B
  const size_t NEED = 1048576u + 16384u + 256u;
  if (ws_size >= NEED) {
    float* part = (float*)d_ws;
    float* scores = (float*)((unsigned char*)d_ws + 1048576u);
    float* svp = scores + 4096;
    mv_kernel<<<520, 512, 0, stream>>>(qm, dm, qs, ds, part, svp);
    reduce_kernel<<<64, 256, 0, stream>>>(part, scores);
    final_kernel<<<1, 64, 0, stream>>>(scores, svp, out);
  } else {
    float* scores = (float*)d_ws;
    float* sv = scores + 4096;
    sv_kernel_fb<<<1, 256, 0, stream>>>(qs, ds, sv);
    mv_gemm_fb<<<dim3(16, 64), 256, 0, stream>>>(qm, dm, scores);
    final_fb<<<1, 64, 0, stream>>>(scores, sv, out);
  }
}

// Round 11
// 52.779 us; speedup vs baseline: 1.7012x; 1.7012x over previous
//
#include <hip/hip_runtime.h>

// ColPali2Loss: sv in-batch softmax CE + mv MaxSim margin loss.
// B=64, Nq=32, Ns=1024, D=128. Outputs: [sv_loss, mv_loss, total] f32.
// r5 structure + 3-buffer counted-vmcnt pipeline (T3/T4-lite) in mv.

typedef __attribute__((ext_vector_type(8))) short short8;
typedef __attribute__((ext_vector_type(4))) float f32x4;

static __device__ __forceinline__ unsigned short f2bf(float f) {
  unsigned int u = __float_as_uint(f);
  u += 0x7fffu + ((u >> 16) & 1u);  // RNE to bf16
  return (unsigned short)(u >> 16);
}

static __device__ __forceinline__ void g2l16(const void* g, void* l) {
  __builtin_amdgcn_global_load_lds(
      (const __attribute__((address_space(1))) unsigned int*)g,
      (__attribute__((address_space(3))) unsigned int*)l, 16, 0, 0);
}

// ---------------- pre-convert: dm -> swizzled bf16, qm -> linear bf16 -----
// dmb layout (bytes): c*262144 + s*256 + ((kc*16) ^ ((s&7)<<4)), kc = 16B grp
// qmb layout: row*256 + k*2   (r5-verified; NDM = 1048576)
__global__ void convert_kernel(const float* __restrict__ qm,
                               const float* __restrict__ dm,
                               unsigned char* __restrict__ dmb,
                               unsigned short* __restrict__ qmb) {
  const int NDM = 1048576;
  const int NT = NDM + 32768;  // + qm 16B-groups
  for (int g = blockIdx.x * 256 + threadIdx.x; g < NT;
       g += gridDim.x * 256) {
    const float* src;
    unsigned char* dst;
    if (g < NDM) {
      const int c = g >> 14;  // 16384 groups per doc
      const int r = g & 16383;
      const int s = r >> 4;
      const int kc = r & 15;
      src = dm + ((size_t)c * 131072 + (size_t)s * 128 + kc * 8);
      dst = dmb + ((size_t)c * 262144 + s * 256 +
                   ((kc * 16) ^ ((s & 7) << 4)));
    } else {
      const int gg = g - NDM;
      const int row = gg >> 4;
      const int kc = gg & 15;
      src = qm + (size_t)row * 128 + kc * 8;
      dst = (unsigned char*)(qmb + (size_t)row * 128 + kc * 8);
    }
    const float4 a = *(const float4*)src;
    const float4 b = *(const float4*)(src + 4);
    short8 w;
    w[0] = (short)f2bf(a.x); w[1] = (short)f2bf(a.y);
    w[2] = (short)f2bf(a.z); w[3] = (short)f2bf(a.w);
    w[4] = (short)f2bf(b.x); w[5] = (short)f2bf(b.y);
    w[6] = (short)f2bf(b.z); w[7] = (short)f2bf(b.w);
    *(short8*)dst = w;
  }
}

// ---------------- fused mv GEMM (+ sv in by==64 blocks) ----------------
// mv blocks: 256 threads / 4 waves; 256 rows x 1 doc c; 16 tiles of 64 s.
// 3-buffer pipeline: stage(t+2) issued before compute(t); vmcnt(4) keeps
// one stage in flight across each barrier (never drain to 0 mid-loop).
// LDS: [0,48K) bf16 tri-buffer | [48K,49K) rowmax
__global__ __launch_bounds__(256, 2) void mv_kernel(
    const unsigned short* __restrict__ qmb,
    const unsigned char* __restrict__ dmb,
    const float* __restrict__ qs, const float* __restrict__ ds,
    float* __restrict__ scores, float* __restrict__ svp) {
  __shared__ __align__(16) unsigned char smem[50176];

  const int tid = threadIdx.x;
  const int ln = tid & 63;
  const int wv = tid >> 6;

  if (blockIdx.y == 64) {
    // ---- sv block: rows 8*rb .. 8*rb+7 of the 64x64 score matrix ----
    const int rb = blockIdx.x;  // 0..7
    float* dl = (float*)smem;   // [64][129] padded f32 (33024 B < 50176)
    for (int i = tid; i < 8192; i += 256)
      dl[(i >> 7) * 129 + (i & 127)] = ds[i];
    __syncthreads();
    const int cc = ln;  // candidate doc = lane
    for (int rr = 0; rr < 2; ++rr) {
      const int row = rb * 8 + wv * 2 + rr;
      const float* q = qs + (size_t)row * 128;
      float acc = 0.f;
#pragma unroll
      for (int k = 0; k < 128; ++k) acc += q[k] * dl[cc * 129 + k];
      float m = acc;
      for (int d = 1; d < 64; d <<= 1) m = fmaxf(m, __shfl_xor(m, d));
      float e = expf(acc - m);
      float ssum = e;
      for (int d = 1; d < 64; d <<= 1) ssum += __shfl_xor(ssum, d);
      const float lp = acc - m - logf(ssum);
      const float diag = __shfl(lp, row);
      if (ln == 0) svp[row] = -diag;
    }
    return;
  }

  const int c = blockIdx.y;
  const int rb = blockIdx.x;  // 0..7 (256 rows each)
  const int lrow = ln & 15;
  const int lkg = ln >> 4;

  // A fragments first (their compiler wait at first use won't force a
  // stage drain beyond vmcnt ordering; issued before stages).
  short8 qf[4][4];
#pragma unroll
  for (int rt = 0; rt < 4; ++rt) {
    const int row = rb * 256 + wv * 64 + rt * 16 + lrow;
    const unsigned short* qp = qmb + (size_t)row * 128 + lkg * 8;
#pragma unroll
    for (int kk = 0; kk < 4; ++kk)
      qf[rt][kk] = *(const short8*)(qp + kk * 32);
  }

  f32x4 maxv[4];
#pragma unroll
  for (int rt = 0; rt < 4; ++rt)
#pragma unroll
    for (int r = 0; r < 4; ++r) maxv[rt][r] = -3.0e38f;

  const unsigned char* dbase = dmb + (size_t)c * 262144;
  float* rowmax = (float*)(smem + 49152);

  // prologue: stage tiles 0 and 1 (4 g2l16 per wave each)
#pragma unroll
  for (int i = 0; i < 4; ++i) {
    const int chunk = wv * 4 + i;
    g2l16(dbase + chunk * 1024 + ln * 16, smem + chunk * 1024);
  }
#pragma unroll
  for (int i = 0; i < 4; ++i) {
    const int chunk = wv * 4 + i;
    g2l16(dbase + 16384 + chunk * 1024 + ln * 16,
          smem + 16384 + chunk * 1024);
  }
  // wait: qf + stage0 done (stage1 still flying), then rendezvous
  asm volatile("s_waitcnt vmcnt(4)" ::: "memory");
  __builtin_amdgcn_s_barrier();

  for (int t = 0; t < 16; ++t) {
    // issue stage t+2 into buf[(t+2)%3] (free since barrier at end of t-1)
    if (t < 14) {
      unsigned char* nxt = smem + ((t + 2) % 3) * 16384;
      const unsigned char* gsrc = dbase + (t + 2) * 16384;
#pragma unroll
      for (int i = 0; i < 4; ++i) {
        const int chunk = wv * 4 + i;
        g2l16(gsrc + chunk * 1024 + ln * 16, nxt + chunk * 1024);
      }
    }
    // compute on buf[t%3]
    const unsigned char* cur = smem + (t % 3) * 16384;
#pragma unroll
    for (int cc = 0; cc < 4; ++cc) {
      const int s = cc * 16 + lrow;
      const unsigned char* bp = cur + s * 256;
      const int swz = (s & 7) << 4;
      short8 df[4];
#pragma unroll
      for (int kk = 0; kk < 4; ++kk)
        df[kk] = *(const short8*)(bp + ((kk * 64 + lkg * 16) ^ swz));
      __builtin_amdgcn_s_setprio(1);
#pragma unroll
      for (int rt = 0; rt < 4; ++rt) {
        f32x4 a = {0.f, 0.f, 0.f, 0.f};
#pragma unroll
        for (int kk = 0; kk < 4; ++kk)
          a = __builtin_amdgcn_mfma_f32_16x16x32_bf16(qf[rt][kk], df[kk], a,
                                                      0, 0, 0);
#pragma unroll
        for (int r = 0; r < 4; ++r) maxv[rt][r] = fmaxf(maxv[rt][r], a[r]);
      }
      __builtin_amdgcn_s_setprio(0);
    }
    // counted wait: stage(t+1) landed; stage(t+2) stays in flight
    if (t < 14) {
      asm volatile("s_waitcnt vmcnt(4)" ::: "memory");
    } else if (t == 14) {
      asm volatile("s_waitcnt vmcnt(0)" ::: "memory");
    }
    if (t < 15) __builtin_amdgcn_s_barrier();
  }

  // max over 16 s-column lanes (C/D: col=lrow, row=lkg*4+r)
#pragma unroll
  for (int rt = 0; rt < 4; ++rt)
#pragma unroll
    for (int r = 0; r < 4; ++r) {
      float v = maxv[rt][r];
      v = fmaxf(v, __shfl_xor(v, 1));
      v = fmaxf(v, __shfl_xor(v, 2));
      v = fmaxf(v, __shfl_xor(v, 4));
      v = fmaxf(v, __shfl_xor(v, 8));
      if (lrow == 0) rowmax[wv * 64 + rt * 16 + lkg * 4 + r] = v;
    }
  __syncthreads();

  // sum the 32 per-n maxes for each of the 8 b's in this row-block
  {
    float v = rowmax[tid];
    v += __shfl_xor(v, 1);
    v += __shfl_xor(v, 2);
    v += __shfl_xor(v, 4);
    v += __shfl_xor(v, 8);
    v += __shfl_xor(v, 16);
    if ((tid & 31) == 0) {
      const int b = rb * 8 + (tid >> 5);
      scores[b * 64 + c] = v;
    }
  }
}

// ---------------- final: sv mean + margin loss + combine ----------------
__global__ void final_kernel(const float* __restrict__ scores,
                             const float* __restrict__ svp,
                             float* __restrict__ out) {
  const int b = threadIdx.x;  // 64
  float sv = svp[b];
  for (int d = 1; d < 64; d <<= 1) sv += __shfl_xor(sv, d);
  sv *= (1.0f / 64.0f);

  const float pos = scores[b * 64 + b];
  float neg = -3.0e38f;
  for (int c = 0; c < 64; ++c) {
    float v = scores[b * 64 + c] - (c == b ? 1.0e6f : 0.0f);
    neg = fmaxf(neg, v);
  }
  const float t = neg - pos;
  float sp = fmaxf(t, 0.f) + log1pf(expf(-fabsf(t)));
  for (int d = 1; d < 64; d <<= 1) sp += __shfl_xor(sp, d);
  if (b == 0) {
    const float mvl = sp / 64.0f;
    out[0] = sv;
    out[1] = mvl;
    out[2] = 0.5f * sv + 0.5f * mvl;
  }
}

// ======================= fallback (round-1, passing) =======================
__global__ void sv_kernel_fb(const float* __restrict__ qs,
                             const float* __restrict__ ds,
                             float* __restrict__ out_sv) {
  __shared__ float sc[64][64];
  const int tid = threadIdx.x;
  for (int p = tid; p < 4096; p += 256) {
    const int b = p >> 6, c = p & 63;
    const float4* qa = (const float4*)(qs + b * 128);
    const float4* da = (const float4*)(ds + c * 128);
    float acc = 0.f;
#pragma unroll
    for (int i = 0; i < 32; ++i) {
      const float4 x = qa[i], y = da[i];
      acc += x.x * y.x + x.y * y.y + x.z * y.z + x.w * y.w;
    }
    sc[b][c] = acc;
  }
  __syncthreads();
  if (tid < 64) {
    float m = -3.0e38f;
    for (int c = 0; c < 64; ++c) m = fmaxf(m, sc[tid][c]);
    float s = 0.f;
    for (int c = 0; c < 64; ++c) s += expf(sc[tid][c] - m);
    float lp = sc[tid][tid] - (m + logf(s));
    for (int d = 1; d < 64; d <<= 1) lp += __shfl_xor(lp, d);
    if (tid == 0) *out_sv = -lp / 64.0f;
  }
}

__global__ __launch_bounds__(256, 4) void mv_gemm_fb(
    const float* __restrict__ qm, const float* __restrict__ dm,
    float* __restrict__ scores) {
  __shared__ unsigned char dtb[64 * 256];
  __shared__ float rowmax[128];
  const int c = blockIdx.y;
  const int rb = blockIdx.x;
  const int tid = threadIdx.x;
  const int ln = tid & 63;
  const int wv = tid >> 6;
  const int lrow = ln & 15;
  const int lkg = ln >> 4;
  short8 qf[2][4];
#pragma unroll
  for (int rt = 0; rt < 2; ++rt) {
    const int row = rb * 128 + wv * 32 + rt * 16 + lrow;
    const float* qp = qm + (size_t)row * 128 + lkg * 8;
#pragma unroll
    for (int kk = 0; kk < 4; ++kk) {
      const float4 a = *(const float4*)(qp + kk * 32);
      const float4 b = *(const float4*)(qp + kk * 32 + 4);
      short8 f;
      f[0] = (short)f2bf(a.x); f[1] = (short)f2bf(a.y);
      f[2] = (short)f2bf(a.z); f[3] = (short)f2bf(a.w);
      f[4] = (short)f2bf(b.x); f[5] = (short)f2bf(b.y);
      f[6] = (short)f2bf(b.z); f[7] = (short)f2bf(b.w);
      qf[rt][kk] = f;
    }
  }
  f32x4 maxv[2];
#pragma unroll
  for (int rt = 0; rt < 2; ++rt)
#pragma unroll
    for (int r = 0; r < 4; ++r) maxv[rt][r] = -3.0e38f;
  const float* dbase = dm + (size_t)c * 1024 * 128;
  for (int t = 0; t < 16; ++t) {
    __syncthreads();
#pragma unroll
    for (int i = 0; i < 4; ++i) {
      const int ch = tid + i * 256;
      const int s = ch >> 4;
      const int kc = ch & 15;
      const float* p = dbase + (size_t)(t * 64 + s) * 128 + kc * 8;
      const float4 a = *(const float4*)p;
      const float4 b = *(const float4*)(p + 4);
      short8 w;
      w[0] = (short)f2bf(a.x); w[1] = (short)f2bf(a.y);
      w[2] = (short)f2bf(a.z); w[3] = (short)f2bf(a.w);
      w[4] = (short)f2bf(b.x); w[5] = (short)f2bf(b.y);
      w[6] = (short)f2bf(b.z); w[7] = (short)f2bf(b.w);
      *(short8*)(dtb + s * 256 + ((kc * 16) ^ ((s & 7) << 4))) = w;
    }
    __syncthreads();
#pragma unroll
    for (int cc = 0; cc < 4; ++cc) {
      const int s = cc * 16 + lrow;
      short8 df[4];
#pragma unroll
      for (int kk = 0; kk < 4; ++kk)
        df[kk] = *(const short8*)(dtb + s * 256 +
                                  ((kk * 64 + lkg * 16) ^ ((s & 7) << 4)));
#pragma unroll
      for (int rt = 0; rt < 2; ++rt) {
        f32x4 acc = {0.f, 0.f, 0.f, 0.f};
#pragma unroll
        for (int kk = 0; kk < 4; ++kk)
          acc = __builtin_amdgcn_mfma_f32_16x16x32_bf16(qf[rt][kk], df[kk],
                                                        acc, 0, 0, 0);
#pragma unroll
        for (int r = 0; r < 4; ++r) maxv[rt][r] = fmaxf(maxv[rt][r], acc[r]);
      }
    }
  }
#pragma unroll
  for (int rt = 0; rt < 2; ++rt)
#pragma unroll
    for (int r = 0; r < 4; ++r) {
      float v = maxv[rt][r];
      v = fmaxf(v, __shfl_xor(v, 1));
      v = fmaxf(v, __shfl_xor(v, 2));
      v = fmaxf(v, __shfl_xor(v, 4));
      v = fmaxf(v, __shfl_xor(v, 8));
      maxv[rt][r] = v;
    }
  if (lrow == 0) {
#pragma unroll
    for (int rt = 0; rt < 2; ++rt)
#pragma unroll
      for (int r = 0; r < 4; ++r)
        rowmax[wv * 32 + rt * 16 + lkg * 4 + r] = maxv[rt][r];
  }
  __syncthreads();
  if (tid < 128) {
    float v = rowmax[tid];
    v += __shfl_xor(v, 1);
    v += __shfl_xor(v, 2);
    v += __shfl_xor(v, 4);
    v += __shfl_xor(v, 8);
    v += __shfl_xor(v, 16);
    if ((tid & 31) == 0) scores[(rb * 4 + (tid >> 5)) * 64 + c] = v;
  }
}

__global__ void final_fb(const float* __restrict__ scores,
                         const float* __restrict__ sv_ptr,
                         float* __restrict__ out) {
  const int b = threadIdx.x;
  const float pos = scores[b * 64 + b];
  float neg = -3.0e38f;
  for (int c = 0; c < 64; ++c) {
    float v = scores[b * 64 + c] - (c == b ? 1.0e6f : 0.0f);
    neg = fmaxf(neg, v);
  }
  const float t = neg - pos;
  float sp = fmaxf(t, 0.f) + log1pf(expf(-fabsf(t)));
  for (int d = 1; d < 64; d <<= 1) sp += __shfl_xor(sp, d);
  if (b == 0) {
    const float mvl = sp / 64.0f;
    const float sv = *sv_ptr;
    out[0] = sv;
    out[1] = mvl;
    out[2] = 0.5f * sv + 0.5f * mvl;
  }
}

extern "C" void kernel_launch(void* const* d_in, const int* in_sizes, int n_in,
                              void* d_out, int out_size, void* d_ws,
                              size_t ws_size, hipStream_t stream) {
  const float* qs = (const float*)d_in[0];  // (64,128)
  const float* ds = (const float*)d_in[1];  // (64,128)
  const float* qm = (const float*)d_in[2];  // (64,32,128)
  const float* dm = (const float*)d_in[3];  // (64,1024,128)
  float* out = (float*)d_out;

  const size_t NEED = 16777216u + 524288u + 16384u + 256u;
  if (ws_size >= NEED) {
    unsigned char* dmb = (unsigned char*)d_ws;                 // 16 MiB
    unsigned short* qmb = (unsigned short*)(dmb + 16777216u);  // 512 KiB
    float* scores = (float*)(dmb + 16777216u + 524288u);       // 16 KiB
    float* svp = scores + 4096;                                // 64 f32
    convert_kernel<<<2048, 256, 0, stream>>>(qm, dm, dmb, qmb);
    mv_kernel<<<dim3(8, 65), 256, 0, stream>>>(qmb, dmb, qs, ds, scores, svp);
    final_kernel<<<1, 64, 0, stream>>>(scores, svp, out);
  } else {
    float* scores = (float*)d_ws;
    float* sv = scores + 4096;
    sv_kernel_fb<<<1, 256, 0, stream>>>(qs, ds, sv);
    mv_gemm_fb<<<dim3(16, 64), 256, 0, stream>>>(qm, dm, scores);
    final_fb<<<1, 64, 0, stream>>>(scores, sv, out);
  }
}